// Round 1
// baseline (274.459 us; speedup 1.0000x reference)
//
#include <hip/hip_runtime.h>

// Sinkhorn loss, restructured as scaling-form Sinkhorn:
//   K = exp(-C/eps) precomputed once (batch-independent)
//   a' = m .* a ./ (a .* (K b) + 1e-6)   (== eps*(log m - lse(M)) + u in log domain)
//   b' = t .* b ./ (b .* (K a') + 1e-6)  (C symmetric -> K^T = K)
//   cost_b = sum_i a_i * sum_j (K_ij * C_ij) * b_j
// Each pass = [N x N] * [N x 32] matvec, shared K across all 32 batches.

#define SN 2304      // 48*48
#define NB 32        // batch
#define JSPLIT 9     // j-range split into 9 chunks of 256
#define JC 256       // j per chunk
#define RPB 16       // rows per block (4 waves x 4 rows)

__device__ __forceinline__ float4 f4zero() { return make_float4(0.f, 0.f, 0.f, 0.f); }

// ---- per-batch mass sums: psum[b] = sum_i (pred[b,0,i] + 1e-9), same for target
__global__ __launch_bounds__(256) void k_sums(const float* __restrict__ pred,
                                              const float* __restrict__ tgt,
                                              float* __restrict__ psum,
                                              float* __restrict__ tsum) {
    const int b = blockIdx.x & 31;
    const bool isP = blockIdx.x < 32;
    const float* src = (isP ? pred : tgt) + (size_t)b * 3 * SN;
    const int t = threadIdx.x;
    float acc = 0.f;
    for (int i = t; i < SN; i += 256) acc += src[i] + 1e-9f;
    #pragma unroll
    for (int off = 32; off; off >>= 1) acc += __shfl_down(acc, off);
    __shared__ float red[4];
    if ((t & 63) == 0) red[t >> 6] = acc;
    __syncthreads();
    if (t == 0) (isP ? psum : tsum)[b] = red[0] + red[1] + red[2] + red[3];
}

// ---- K = exp(-C/eps), vectorized float4, grid covers N*N/4 exactly
__global__ __launch_bounds__(256) void k_expK(const float* __restrict__ C,
                                              float* __restrict__ Km) {
    const int idx = blockIdx.x * 256 + threadIdx.x;
    float4 c = ((const float4*)C)[idx];
    float4 k;
    k.x = __expf(c.x * -100.0f);
    k.y = __expf(c.y * -100.0f);
    k.z = __expf(c.z * -100.0f);
    k.w = __expf(c.w * -100.0f);
    ((float4*)Km)[idx] = k;
}

// ---- transposed mass arrays m[i*32+b], init a=b=1
__global__ __launch_bounds__(256) void k_init(const float* __restrict__ pred,
                                              const float* __restrict__ tgt,
                                              const float* __restrict__ psum,
                                              const float* __restrict__ tsum,
                                              float* __restrict__ msrc,
                                              float* __restrict__ mtgt,
                                              float* __restrict__ av,
                                              float* __restrict__ bv) {
    const int idx = blockIdx.x * 256 + threadIdx.x;   // 0..73727
    const int i = idx >> 5, b = idx & 31;
    const size_t src = (size_t)b * 3 * SN + i;
    msrc[idx] = (pred[src] + 1e-9f) / psum[b];
    mtgt[idx] = (tgt[src] + 1e-9f) / tsum[b];
    av[idx] = 1.0f;
    bv[idx] = 1.0f;
}

// ---- partial matvec: S_part[js][i][b] = sum_{j in chunk js} K[i][j] * x[j][b]
// If WITHC, K element is multiplied by C element on the fly (final cost pass).
// Block: 256 threads = 4 waves; wave w owns rows row0..row0+3; lane covers
// 4 batches (float4) and 1/8 of the j-chunk; shuffle-reduce across j-sublanes.
template <bool WITHC>
__global__ __launch_bounds__(256) void k_matvec(const float* __restrict__ Km,
                                                const float* __restrict__ Cm,
                                                const float* __restrict__ x,
                                                float* __restrict__ S_part) {
    __shared__ float X_lds[JC * NB];   // 32 KB
    const int t = threadIdx.x;
    const int rowg = blockIdx.x / JSPLIT;
    const int js = blockIdx.x % JSPLIT;
    const int jbase = js * JC;

    // stage X chunk (x[jbase..jbase+256) x 32 batches, [j][b] layout) -> LDS
    const float4* xg = (const float4*)(x + (size_t)jbase * NB);
    float4* xl = (float4*)X_lds;
    #pragma unroll
    for (int q = 0; q < 8; ++q) xl[t + q * 256] = xg[t + q * 256];
    __syncthreads();

    const int w = t >> 6;
    const int l = t & 63;
    const int jh = l >> 3;            // 0..7: j sub-offset
    const int b4 = (l & 7) << 2;      // batch group of 4
    const int row0 = rowg * RPB + w * 4;

    const float* Kr = Km + (size_t)row0 * SN + jbase + jh;
    const float* Cr = WITHC ? (Cm + (size_t)row0 * SN + jbase + jh) : nullptr;

    float4 a0 = f4zero(), a1 = f4zero(), a2 = f4zero(), a3 = f4zero();

    #pragma unroll 4
    for (int j2 = 0; j2 < JC / 8; ++j2) {
        const int jo = j2 << 3;
        const int j = jo + jh;
        const float4 xv = *(const float4*)&X_lds[j * NB + b4];
        float k0 = Kr[(size_t)0 * SN + jo];
        float k1 = Kr[(size_t)1 * SN + jo];
        float k2 = Kr[(size_t)2 * SN + jo];
        float k3 = Kr[(size_t)3 * SN + jo];
        if (WITHC) {
            k0 *= Cr[(size_t)0 * SN + jo];
            k1 *= Cr[(size_t)1 * SN + jo];
            k2 *= Cr[(size_t)2 * SN + jo];
            k3 *= Cr[(size_t)3 * SN + jo];
        }
        a0.x += k0 * xv.x; a0.y += k0 * xv.y; a0.z += k0 * xv.z; a0.w += k0 * xv.w;
        a1.x += k1 * xv.x; a1.y += k1 * xv.y; a1.z += k1 * xv.z; a1.w += k1 * xv.w;
        a2.x += k2 * xv.x; a2.y += k2 * xv.y; a2.z += k2 * xv.z; a2.w += k2 * xv.w;
        a3.x += k3 * xv.x; a3.y += k3 * xv.y; a3.z += k3 * xv.z; a3.w += k3 * xv.w;
    }

    // reduce over jh (lanes differing by 8,16,32)
    #pragma unroll
    for (int off = 8; off < 64; off <<= 1) {
        a0.x += __shfl_down(a0.x, off); a0.y += __shfl_down(a0.y, off);
        a0.z += __shfl_down(a0.z, off); a0.w += __shfl_down(a0.w, off);
        a1.x += __shfl_down(a1.x, off); a1.y += __shfl_down(a1.y, off);
        a1.z += __shfl_down(a1.z, off); a1.w += __shfl_down(a1.w, off);
        a2.x += __shfl_down(a2.x, off); a2.y += __shfl_down(a2.y, off);
        a2.z += __shfl_down(a2.z, off); a2.w += __shfl_down(a2.w, off);
        a3.x += __shfl_down(a3.x, off); a3.y += __shfl_down(a3.y, off);
        a3.z += __shfl_down(a3.z, off); a3.w += __shfl_down(a3.w, off);
    }
    if (jh == 0) {   // lanes 0..7, each holds one batch-group of 4
        float4* Sp = (float4*)(S_part + ((size_t)js * SN + row0) * NB + b4);
        Sp[0] = a0;          // row0+0   (row stride = 32 floats = 8 float4)
        Sp[8] = a1;
        Sp[16] = a2;
        Sp[24] = a3;
    }
}

// ---- combine j-split partials, apply scaling update y = m*y/(y*S + 1e-6)
__global__ __launch_bounds__(256) void k_update(const float* __restrict__ S_part,
                                                const float* __restrict__ m_t,
                                                float* __restrict__ y) {
    const int idx = blockIdx.x * 256 + threadIdx.x;  // float4 index over 18432
    float4 s = f4zero();
    #pragma unroll
    for (int h = 0; h < JSPLIT; ++h) {
        float4 v = ((const float4*)S_part)[(size_t)h * (SN * NB / 4) + idx];
        s.x += v.x; s.y += v.y; s.z += v.z; s.w += v.w;
    }
    float4 yv = ((const float4*)y)[idx];
    float4 mv = ((const float4*)m_t)[idx];
    float4 r;
    r.x = mv.x * yv.x / (yv.x * s.x + 1e-6f);
    r.y = mv.y * yv.y / (yv.y * s.y + 1e-6f);
    r.z = mv.z * yv.z / (yv.z * s.z + 1e-6f);
    r.w = mv.w * yv.w / (yv.w * s.w + 1e-6f);
    ((float4*)y)[idx] = r;
}

// ---- cost[b] = sum_i a[i][b] * (sum_h S_part[h][i][b])   (S_part from K*C pass)
__global__ __launch_bounds__(256) void k_cost(const float* __restrict__ S_part,
                                              const float* __restrict__ a_t,
                                              float* __restrict__ out) {
    const int b = blockIdx.x;
    const int t = threadIdx.x;
    float acc = 0.f;
    for (int i = t; i < SN; i += 256) {
        float s = 0.f;
        #pragma unroll
        for (int h = 0; h < JSPLIT; ++h) s += S_part[((size_t)h * SN + i) * NB + b];
        acc += a_t[(size_t)i * NB + b] * s;
    }
    #pragma unroll
    for (int off = 32; off; off >>= 1) acc += __shfl_down(acc, off);
    __shared__ float red[4];
    if ((t & 63) == 0) red[t >> 6] = acc;
    __syncthreads();
    if (t == 0) out[b] = red[0] + red[1] + red[2] + red[3];
}

extern "C" void kernel_launch(void* const* d_in, const int* in_sizes, int n_in,
                              void* d_out, int out_size, void* d_ws, size_t ws_size,
                              hipStream_t stream) {
    const float* pred = (const float*)d_in[0];   // [32,3,48,48]
    const float* tgt  = (const float*)d_in[1];   // [32,3,48,48]
    const float* C    = (const float*)d_in[2];   // [2304,2304]
    float* out = (float*)d_out;                  // [32]

    float* ws = (float*)d_ws;
    float* Km   = ws;                               // N*N          = 5308416
    float* Sp   = Km + (size_t)SN * SN;             // 9*N*32       =  663552
    float* av   = Sp + (size_t)JSPLIT * SN * NB;    // N*32
    float* bv   = av + SN * NB;
    float* msrc = bv + SN * NB;
    float* mtgt = msrc + SN * NB;
    float* psum = mtgt + SN * NB;                   // 32
    float* tsum = psum + NB;                        // 32
    // total ~25.1 MB of d_ws

    k_sums<<<64, 256, 0, stream>>>(pred, tgt, psum, tsum);
    k_expK<<<SN * SN / 1024, 256, 0, stream>>>(C, Km);
    k_init<<<SN * NB / 256, 256, 0, stream>>>(pred, tgt, psum, tsum, msrc, mtgt, av, bv);

    const int MG = (SN / RPB) * JSPLIT;   // 1296 blocks
    for (int it = 0; it < 5; ++it) {
        k_matvec<false><<<MG, 256, 0, stream>>>(Km, nullptr, bv, Sp);
        k_update<<<72, 256, 0, stream>>>(Sp, msrc, av);
        k_matvec<false><<<MG, 256, 0, stream>>>(Km, nullptr, av, Sp);
        k_update<<<72, 256, 0, stream>>>(Sp, mtgt, bv);
    }
    k_matvec<true><<<MG, 256, 0, stream>>>(Km, C, bv, Sp);
    k_cost<<<32, 256, 0, stream>>>(Sp, av, out);
}

// Round 2
// 243.949 us; speedup vs baseline: 1.1251x; 1.1251x over previous
//
#include <hip/hip_runtime.h>

// Sinkhorn in scaling form, 15 dispatches:
//   k_sums, k_minit, pass0 (C->K=exp(-C/eps), S=K*1, a1=m/(S+1e-6)),
//   pass1 (S=K*a, b1=t/(S+1e-6)), 8x generic pass, final (S=(K.C)*b, cost), k_out.
// Pass kernel: 256 blocks x 512 thr; block owns 9 rows; waves take disjoint
// 32-j sub-windows of LDS-staged 256-j x-chunks (XOR-swizzled, db);
// K read float4 lane-contiguous from L2 with 1-window software prefetch.

#define SN 2304
#define NBAT 32
#define ROWS 9
#define NBLK 256
#define NTHR 512
#define SNF4 576   // SN/4

__device__ __forceinline__ void fma4(float4& a, float k, const float4 x) {
    a.x = fmaf(k, x.x, a.x);
    a.y = fmaf(k, x.y, a.y);
    a.z = fmaf(k, x.z, a.z);
    a.w = fmaf(k, x.w, a.w);
}

__global__ __launch_bounds__(256) void k_sums(const float* __restrict__ pred,
                                              const float* __restrict__ tgt,
                                              float* __restrict__ psum,
                                              float* __restrict__ tsum) {
    const int b = blockIdx.x & 31;
    const bool isP = blockIdx.x < 32;
    const float* src = (isP ? pred : tgt) + (size_t)b * 3 * SN;
    const int t = threadIdx.x;
    float acc = 0.f;
    for (int i = t; i < SN; i += 256) acc += src[i] + 1e-9f;
    #pragma unroll
    for (int off = 32; off; off >>= 1) acc += __shfl_down(acc, off);
    __shared__ float red[4];
    if ((t & 63) == 0) red[t >> 6] = acc;
    __syncthreads();
    if (t == 0) (isP ? psum : tsum)[b] = red[0] + red[1] + red[2] + red[3];
}

__global__ __launch_bounds__(256) void k_minit(const float* __restrict__ pred,
                                               const float* __restrict__ tgt,
                                               const float* __restrict__ psum,
                                               const float* __restrict__ tsum,
                                               float* __restrict__ msrc,
                                               float* __restrict__ mtgt) {
    const int b = blockIdx.x;
    const float ps = psum[b], ts = tsum[b];
    #pragma unroll
    for (int k = 0; k < 9; ++k) {
        const int i = threadIdx.x + k * 256;
        const float pv = pred[(size_t)b * 3 * SN + i];
        const float tv = tgt[(size_t)b * 3 * SN + i];
        msrc[(size_t)i * NBAT + b] = (pv + 1e-9f) / ps;
        mtgt[(size_t)i * NBAT + b] = (tv + 1e-9f) / ts;
    }
}

// MODE 0: Ksrc=C, build+store K, x implicit ones, yold=1, update yupd with mvec
// MODE 1: Ksrc=K_ws, x staged, yold=1, update
// MODE 2: Ksrc=K_ws, x staged, yold from yold_v, update
// MODE 3: Ksrc=C (recompute K.C on the fly), x staged, cost partials -> part
template <int MODE>
__global__ __launch_bounds__(NTHR, 2) void k_pass(
        const float* __restrict__ Ksrc,
        float* __restrict__ Kout,
        const float* __restrict__ xg,
        const float* __restrict__ mvec,
        const float* __restrict__ yold_v,
        float* __restrict__ yupd,
        const float* __restrict__ across,
        float* __restrict__ part) {
    extern __shared__ char smem[];
    float4* xbuf   = (float4*)smem;                 // 2 x 2048 float4 = 64 KB
    float*  S_part = (float*)(smem + 65536);        // 8*288 = 9216 B
    float*  c_lds  = S_part + 2304;                 // 288 floats

    const int t   = threadIdx.x;
    const int blk = blockIdx.x;
    const int r0  = blk * ROWS;
    const int w   = t >> 6;       // wave 0..7 -> 32-j sub-window within chunk
    const int l   = t & 63;
    const int jl  = l & 7;        // 8 j-lanes (f4 -> 32 j per window)
    const int bl  = l >> 3;       // 8 batch-lanes (4 batches each)
    const int sg  = t & 7;        // staging: f4 batch-group
    const int sj  = t >> 3;       // staging: j within chunk

    const float4* Kf4 = (const float4*)Ksrc;
    const float4* xf4 = (const float4*)xg;

    constexpr bool HASX  = (MODE != 0);
    constexpr bool FROMC = (MODE == 0 || MODE == 3);

    float4 acc[ROWS];
    #pragma unroll
    for (int r = 0; r < ROWS; ++r) acc[r] = make_float4(0.f, 0.f, 0.f, 0.f);

    // constant LDS read offsets for this lane (XOR-swizzled)
    int xidx[4];
    #pragma unroll
    for (int jj = 0; jj < 4; ++jj) {
        const int jloc = w * 32 + jl * 4 + jj;
        xidx[jj] = jloc * 8 + (bl ^ (jloc & 7));
    }

    float4 st[4];
    if (HASX) {
        #pragma unroll
        for (int rep = 0; rep < 4; ++rep)
            st[rep] = xf4[(size_t)(sj + 64 * rep) * 8 + sg];
        #pragma unroll
        for (int rep = 0; rep < 4; ++rep) {
            const int jr = sj + 64 * rep;
            xbuf[jr * 8 + (sg ^ (jr & 7))] = st[rep];
        }
        __syncthreads();
    }

    // prefetch K for chunk 0
    float4 kn[ROWS];
    #pragma unroll
    for (int r = 0; r < ROWS; ++r)
        kn[r] = Kf4[(size_t)(r0 + r) * SNF4 + w * 8 + jl];

    #pragma unroll 2
    for (int c = 0; c < 9; ++c) {
        float4 kc[ROWS];
        #pragma unroll
        for (int r = 0; r < ROWS; ++r) kc[r] = kn[r];
        if (c < 8) {
            #pragma unroll
            for (int r = 0; r < ROWS; ++r)
                kn[r] = Kf4[(size_t)(r0 + r) * SNF4 + (c + 1) * 64 + w * 8 + jl];
            if (HASX) {
                #pragma unroll
                for (int rep = 0; rep < 4; ++rep)
                    st[rep] = xf4[(size_t)((c + 1) * 256 + sj + 64 * rep) * 8 + sg];
            }
        }
        if (FROMC) {
            #pragma unroll
            for (int r = 0; r < ROWS; ++r) {
                const float4 cv = kc[r];
                float4 kv;
                kv.x = __expf(cv.x * -100.f); kv.y = __expf(cv.y * -100.f);
                kv.z = __expf(cv.z * -100.f); kv.w = __expf(cv.w * -100.f);
                if (MODE == 3) { kv.x *= cv.x; kv.y *= cv.y; kv.z *= cv.z; kv.w *= cv.w; }
                kc[r] = kv;
                if (MODE == 0 && bl == 0)
                    ((float4*)Kout)[(size_t)(r0 + r) * SNF4 + c * 64 + w * 8 + jl] = kv;
            }
        }
        // compute window
        float4 xq[4];
        if (HASX) {
            const float4* xb = xbuf + (c & 1) * 2048;
            #pragma unroll
            for (int jj = 0; jj < 4; ++jj) xq[jj] = xb[xidx[jj]];
        } else {
            #pragma unroll
            for (int jj = 0; jj < 4; ++jj) xq[jj] = make_float4(1.f, 1.f, 1.f, 1.f);
        }
        #pragma unroll
        for (int r = 0; r < ROWS; ++r) {
            fma4(acc[r], kc[r].x, xq[0]);
            fma4(acc[r], kc[r].y, xq[1]);
            fma4(acc[r], kc[r].z, xq[2]);
            fma4(acc[r], kc[r].w, xq[3]);
        }
        if (HASX) {
            if (c < 8) {
                float4* wb = xbuf + ((c + 1) & 1) * 2048;
                #pragma unroll
                for (int rep = 0; rep < 4; ++rep) {
                    const int jr = sj + 64 * rep;
                    wb[jr * 8 + (sg ^ (jr & 7))] = st[rep];
                }
            }
            __syncthreads();
        }
    }

    // reduce over the 8 j-lanes
    #pragma unroll
    for (int r = 0; r < ROWS; ++r) {
        float4 a = acc[r];
        #pragma unroll
        for (int off = 1; off <= 4; off <<= 1) {
            a.x += __shfl_down(a.x, off);
            a.y += __shfl_down(a.y, off);
            a.z += __shfl_down(a.z, off);
            a.w += __shfl_down(a.w, off);
        }
        acc[r] = a;
    }
    if (jl == 0) {
        #pragma unroll
        for (int r = 0; r < ROWS; ++r)
            *(float4*)&S_part[w * 288 + r * 32 + bl * 4] = acc[r];
    }
    __syncthreads();

    if (MODE == 3) {
        if (t < 288) {
            float s = 0.f;
            #pragma unroll
            for (int ww = 0; ww < 8; ++ww) s += S_part[ww * 288 + t];
            const int r = t >> 5, b = t & 31;
            c_lds[t] = across[(size_t)(r0 + r) * NBAT + b] * s;
        }
        __syncthreads();
        if (t < 32) {
            float p = 0.f;
            #pragma unroll
            for (int r = 0; r < ROWS; ++r) p += c_lds[r * 32 + t];
            part[blk * NBAT + t] = p;
        }
    } else {
        if (t < 288) {
            float s = 0.f;
            #pragma unroll
            for (int ww = 0; ww < 8; ++ww) s += S_part[ww * 288 + t];
            const int r = t >> 5, b = t & 31;
            const size_t yi = (size_t)(r0 + r) * NBAT + b;
            const float yo = (MODE == 2) ? yold_v[yi] : 1.f;
            yupd[yi] = mvec[yi] * yo / (yo * s + 1e-6f);
        }
    }
}

__global__ __launch_bounds__(256) void k_out(const float* __restrict__ part,
                                             float* __restrict__ out) {
    __shared__ float l[256];
    const int t = threadIdx.x;
    const int b = t & 31, g = t >> 5;
    float s = 0.f;
    for (int k = g; k < NBLK; k += 8) s += part[(size_t)k * NBAT + b];
    l[t] = s;
    __syncthreads();
    if (t < 32) {
        float o = 0.f;
        #pragma unroll
        for (int g2 = 0; g2 < 8; ++g2) o += l[g2 * 32 + t];
        out[t] = o;
    }
}

extern "C" void kernel_launch(void* const* d_in, const int* in_sizes, int n_in,
                              void* d_out, int out_size, void* d_ws, size_t ws_size,
                              hipStream_t stream) {
    const float* pred = (const float*)d_in[0];
    const float* tgt  = (const float*)d_in[1];
    const float* C    = (const float*)d_in[2];
    float* out = (float*)d_out;

    float* ws = (float*)d_ws;
    float* K_ws  = ws;                               // SN*SN
    float* m_src = K_ws + (size_t)SN * SN;           // SN*32
    float* m_tgt = m_src + (size_t)SN * NBAT;
    float* ya    = m_tgt + (size_t)SN * NBAT;
    float* yb    = ya + (size_t)SN * NBAT;
    float* psum  = yb + (size_t)SN * NBAT;           // 32
    float* tsum  = psum + NBAT;                      // 32
    float* part  = tsum + NBAT;                      // 256*32

    const size_t SH = 65536 + 9216 + 1152;           // 75904 B dynamic LDS

    hipFuncSetAttribute((const void*)k_pass<0>, hipFuncAttributeMaxDynamicSharedMemorySize, (int)SH);
    hipFuncSetAttribute((const void*)k_pass<1>, hipFuncAttributeMaxDynamicSharedMemorySize, (int)SH);
    hipFuncSetAttribute((const void*)k_pass<2>, hipFuncAttributeMaxDynamicSharedMemorySize, (int)SH);
    hipFuncSetAttribute((const void*)k_pass<3>, hipFuncAttributeMaxDynamicSharedMemorySize, (int)SH);

    k_sums<<<64, 256, 0, stream>>>(pred, tgt, psum, tsum);
    k_minit<<<32, 256, 0, stream>>>(pred, tgt, psum, tsum, m_src, m_tgt);

    // pass 0: build K, S = K*1, a = m_src/(S+1e-6)
    k_pass<0><<<NBLK, NTHR, SH, stream>>>(C, K_ws, nullptr, m_src, nullptr, ya, nullptr, nullptr);
    // pass 1: S = K*a, b = m_tgt/(S+1e-6)
    k_pass<1><<<NBLK, NTHR, SH, stream>>>(K_ws, nullptr, ya, m_tgt, nullptr, yb, nullptr, nullptr);
    for (int it = 1; it < 5; ++it) {
        k_pass<2><<<NBLK, NTHR, SH, stream>>>(K_ws, nullptr, yb, m_src, ya, ya, nullptr, nullptr);
        k_pass<2><<<NBLK, NTHR, SH, stream>>>(K_ws, nullptr, ya, m_tgt, yb, yb, nullptr, nullptr);
    }
    // final: S = (K.C)*b, cost partials
    k_pass<3><<<NBLK, NTHR, SH, stream>>>(C, nullptr, yb, nullptr, nullptr, nullptr, ya, part);
    k_out<<<1, 256, 0, stream>>>(part, out);
}